// Round 14
// baseline (1705.552 us; speedup 1.0000x reference)
//
#include <hip/hip_runtime.h>
#include <stdint.h>

typedef unsigned short u16;
typedef float f32x4 __attribute__((ext_vector_type(4)));
typedef short bf16x8 __attribute__((ext_vector_type(8)));

// ---------- helpers ----------
__device__ __forceinline__ u16 f2bu(float f) {           // fp32 -> bf16 (RNE)
  uint32_t x = __builtin_bit_cast(uint32_t, f);
  x += 0x7fffu + ((x >> 16) & 1u);
  return (u16)(x >> 16);
}
__device__ __forceinline__ float b2f(u16 u) {            // bf16 -> fp32 (exact)
  return __builtin_bit_cast(float, (uint32_t)u << 16);
}
__device__ __forceinline__ void gll16(const void* g, void* l) {
  __builtin_amdgcn_global_load_lds(
      (const __attribute__((address_space(1))) void*)g,
      (__attribute__((address_space(3))) void*)l, 16, 0, 0);
}

// ---------- fp32 -> bf16 convert ----------
__global__ __launch_bounds__(256) void cvt_f32_bf16_kernel(
    const float* __restrict__ in, u16* __restrict__ out, int n4) {
  int i = blockIdx.x * 256 + threadIdx.x;
  const int stride = gridDim.x * 256;
  for (; i < n4; i += stride) {
    float4 f = reinterpret_cast<const float4*>(in)[i];
    ushort4 o;
    o.x = f2bu(f.x); o.y = f2bu(f.y); o.z = f2bu(f.z); o.w = f2bu(f.w);
    reinterpret_cast<ushort4*>(out)[i] = o;
  }
}

// ---------- 128x256 GEMM, 8 waves (2Mx4N of 64x64), BK=64, full read-hoist --
// C[m,n] = sum_k A[m,k]*B[n,k] + bias[n], bf16 in/out, fp32 accum.
// r13 model: per-iter time = ds_read floor + MFMA floor (SUM, not max) --
// barrier-locked read bursts serialize the pipes. Fix needs ALL of a tile's
// fragments hoisted before any MFMA so late reads overlap early MFMAs via
// the compiler's fine lgkmcnt. That needs acc=64 AGPR + 16 frag regs, which
// only fits at a 64x64 wave tile with a 512-thread block (~170/256 regs at
// 2 waves/SIMD). BK=64 dbuf = 96KB LDS, ONE barrier per K-tile. Both-sides
// 3-bit involution slot3' = slot3 ^ (row&7) (0-conflict, r12-proven).
// setprio removed (possible scheduler fence; null for lockstep per m190).
__global__ __launch_bounds__(512, 2) void gemm_bt_bias(
    const u16* __restrict__ A, const u16* __restrict__ Bw,
    const float* __restrict__ bias, u16* __restrict__ C,
    int N, int K, int lda, int ldc, int ntn) {
  __shared__ u16 ldsA[2][8192];    // [buf][128 rows * 64 cols] = 16KB/buf
  __shared__ u16 ldsB[2][16384];   // [buf][256 rows * 64 cols] = 32KB/buf
  const int tid = threadIdx.x;
  const int lane = tid & 63, wid = tid >> 6;   // wid 0..7
  const int wr = wid >> 2, wc = wid & 3;        // wave grid 2 (M) x 4 (N)
  const int fr = lane & 15, kg = lane >> 4;

  // XCD-aware swizzle (grid % 8 == 0 for both calls)
  const int cpx = (int)gridDim.x >> 3;
  const int bid = blockIdx.x;
  const int sid = (bid & 7) * cpx + (bid >> 3);
  const int mt = sid / ntn, nt = sid % ntn;

  // staging: slot s = tid + j*512; row = s>>3 (j adds 64 rows), slot3 = s&7.
  // row&7 = (tid>>3)&7 invariant (64 % 8 == 0). Source col8 pre-swizzled.
  const int srow = tid >> 3;                    // 0..63
  const int sc8 = (tid & 7) ^ (srow & 7);
  const u16* Ag = A + (size_t)(mt * 128 + srow) * lda + sc8 * 8;
  const u16* Bg = Bw + (size_t)(nt * 256 + srow) * K + sc8 * 8;
  const size_t arstep = (size_t)64 * lda;      // +64 rows per j
  const size_t brstep = (size_t)64 * K;

  // fragment read bases (u16, row stride 64); slot3 = ((kh<<2)|kg) ^ (fr&7)
  const int fx = fr & 7;
  const int aoff = (wr * 64 + fr) * 64;         // + mi*1024 + slot3*8
  const int boff = (wc * 64 + fr) * 64;         // + nj*1024 + slot3*8

  f32x4 acc[4][4];
#pragma unroll
  for (int i = 0; i < 4; i++)
#pragma unroll
    for (int j = 0; j < 4; j++) acc[i][j] = f32x4{0.f, 0.f, 0.f, 0.f};

  const int NT = K >> 6;

#define STAGE(b, kt) do {                                                  \
    const u16* a_ = Ag + (size_t)(kt) * 64;                                \
    const u16* b_ = Bg + (size_t)(kt) * 64;                                \
    gll16(a_,              &ldsA[(b)][wid * 512]);                         \
    gll16(a_ + arstep,     &ldsA[(b)][4096 + wid * 512]);                  \
    gll16(b_,              &ldsB[(b)][wid * 512]);                         \
    gll16(b_ + brstep,     &ldsB[(b)][4096 + wid * 512]);                  \
    gll16(b_ + 2 * brstep, &ldsB[(b)][8192 + wid * 512]);                  \
    gll16(b_ + 3 * brstep, &ldsB[(b)][12288 + wid * 512]);                 \
  } while (0)

  STAGE(0, 0);
  __syncthreads();              // tile 0 landed (vmcnt(0) drain)

  const int s0 = kg ^ fx;            // kh=0 slot
  const int s1 = (4 | kg) ^ fx;      // kh=1 slot

  for (int t = 0; t < NT; t++) {
    const int cur = t & 1;
    if (t + 1 < NT) STAGE(cur ^ 1, t + 1);   // prefetch next tile
    const u16* As = &ldsA[cur][0];
    const u16* Bs = &ldsB[cur][0];

    // ---- hoist ALL 16 fragment reads before any MFMA ----
    bf16x8 a0[4], b0[4], a1[4], b1[4];
#pragma unroll
    for (int mi = 0; mi < 4; mi++)
      a0[mi] = *(const bf16x8*)&As[aoff + mi * 1024 + s0 * 8];
#pragma unroll
    for (int nj = 0; nj < 4; nj++)
      b0[nj] = *(const bf16x8*)&Bs[boff + nj * 1024 + s0 * 8];
#pragma unroll
    for (int mi = 0; mi < 4; mi++)
      a1[mi] = *(const bf16x8*)&As[aoff + mi * 1024 + s1 * 8];
#pragma unroll
    for (int nj = 0; nj < 4; nj++)
      b1[nj] = *(const bf16x8*)&Bs[boff + nj * 1024 + s1 * 8];

    // kh=0 MFMAs overlap the in-flight kh=1 reads (fine lgkmcnt)
#pragma unroll
    for (int mi = 0; mi < 4; mi++)
#pragma unroll
      for (int nj = 0; nj < 4; nj++)
        acc[mi][nj] = __builtin_amdgcn_mfma_f32_16x16x32_bf16(
            a0[mi], b0[nj], acc[mi][nj], 0, 0, 0);
#pragma unroll
    for (int mi = 0; mi < 4; mi++)
#pragma unroll
      for (int nj = 0; nj < 4; nj++)
        acc[mi][nj] = __builtin_amdgcn_mfma_f32_16x16x32_bf16(
            a1[mi], b1[nj], acc[mi][nj], 0, 0, 0);
    __syncthreads();   // next tile landed + this tile's reads done (WAR safe)
  }
#undef STAGE

  // C/D layout per 16x16 frag: col = lane&15, row = (lane>>4)*4 + reg
  const int crow0 = mt * 128 + wr * 64 + kg * 4;
  const int ccol0 = nt * 256 + wc * 64 + fr;
#pragma unroll
  for (int nj = 0; nj < 4; nj++) {
    const int col = ccol0 + nj * 16;
    const float bb = bias[col];
#pragma unroll
    for (int mi = 0; mi < 4; mi++) {
      const int r0 = crow0 + mi * 16;
      f32x4 v = acc[mi][nj];
#pragma unroll
      for (int r = 0; r < 4; r++)
        C[(size_t)(r0 + r) * ldc + col] = f2bu(v[r] + bb);
    }
  }
}

// ---------- tiny attention: S=3, 16 heads of d=64 (grid-stride) ----------
// Writes ctx IN-PLACE into the k-slice (cols 1024..2047) of qkv.
__global__ __launch_bounds__(256) void attn3_kernel(
    u16* __restrict__ qkv) {
  const int tid = threadIdx.x;
  const int lane = tid & 63, wid = tid >> 6;
  const int nunit = 32768 * 4;
  for (int unit = blockIdx.x * 4 + wid; unit < nunit; unit += gridDim.x * 4) {
    const int b = unit >> 2, hg = unit & 3;
    const size_t qbase = (size_t)b * 3 * 3072 + hg * 256 + lane * 4;

    float q[3][4], k[3][4], v[3][4];
#pragma unroll
    for (int s = 0; s < 3; s++) {
      ushort4 uq = *(const ushort4*)(qkv + qbase + (size_t)s * 3072);
      ushort4 uk = *(const ushort4*)(qkv + qbase + (size_t)s * 3072 + 1024);
      ushort4 uv = *(const ushort4*)(qkv + qbase + (size_t)s * 3072 + 2048);
      q[s][0] = b2f(uq.x); q[s][1] = b2f(uq.y); q[s][2] = b2f(uq.z); q[s][3] = b2f(uq.w);
      k[s][0] = b2f(uk.x); k[s][1] = b2f(uk.y); k[s][2] = b2f(uk.z); k[s][3] = b2f(uk.w);
      v[s][0] = b2f(uv.x); v[s][1] = b2f(uv.y); v[s][2] = b2f(uv.z); v[s][3] = b2f(uv.w);
    }

    float sc[3][3];
#pragma unroll
    for (int i = 0; i < 3; i++)
#pragma unroll
      for (int j = 0; j < 3; j++) {
        float p = q[i][0] * k[j][0] + q[i][1] * k[j][1] +
                  q[i][2] * k[j][2] + q[i][3] * k[j][3];
        p += __shfl_xor(p, 1);
        p += __shfl_xor(p, 2);
        p += __shfl_xor(p, 4);
        p += __shfl_xor(p, 8);   // 16-lane group = one head's 64 dims
        sc[i][j] = p;
      }

    float o[3][4];
#pragma unroll
    for (int i = 0; i < 3; i++) {
      float mx = fmaxf(sc[i][0], fmaxf(sc[i][1], sc[i][2]));
      float e0 = __expf((sc[i][0] - mx) * 0.125f);
      float e1 = __expf((sc[i][1] - mx) * 0.125f);
      float e2 = __expf((sc[i][2] - mx) * 0.125f);
      float inv = 1.f / (e0 + e1 + e2);
      e0 *= inv; e1 *= inv; e2 *= inv;
#pragma unroll
      for (int d = 0; d < 4; d++)
        o[i][d] = e0 * v[0][d] + e1 * v[1][d] + e2 * v[2][d];
    }

#pragma unroll
    for (int i = 0; i < 3; i++) {
      ushort4 ov;
      ov.x = f2bu(o[i][0]); ov.y = f2bu(o[i][1]);
      ov.z = f2bu(o[i][2]); ov.w = f2bu(o[i][3]);
      *(ushort4*)(qkv + qbase + (size_t)i * 3072 + 1024) = ov;
    }
  }
}

// ---------- residual + LayerNorm: wave per row of 1024 ----------
__global__ __launch_bounds__(256) void ln_kernel(
    const u16* __restrict__ slots_bf, const u16* __restrict__ ao,
    const float* __restrict__ g, const float* __restrict__ bvec,
    float* __restrict__ out) {
  const int tid = threadIdx.x;
  const int lane = tid & 63, wid = tid >> 6;
  const int row = blockIdx.x * 4 + wid;
  const size_t rb = (size_t)row * 1024;
  const size_t ab = (size_t)row * 3072;

  float y[16];
  float sum = 0.f, sq = 0.f;
#pragma unroll
  for (int c = 0; c < 4; c++) {
    const int col = c * 256 + lane * 4;
    ushort4 s4 = *(const ushort4*)(slots_bf + rb + col);
    ushort4 a4 = *(const ushort4*)(ao + ab + col);
    float y0 = b2f(s4.x) + b2f(a4.x), y1 = b2f(s4.y) + b2f(a4.y);
    float y2 = b2f(s4.z) + b2f(a4.z), y3 = b2f(s4.w) + b2f(a4.w);
    y[c * 4 + 0] = y0; y[c * 4 + 1] = y1; y[c * 4 + 2] = y2; y[c * 4 + 3] = y3;
    sum += y0 + y1 + y2 + y3;
    sq += y0 * y0 + y1 * y1 + y2 * y2 + y3 * y3;
  }
#pragma unroll
  for (int m = 1; m < 64; m <<= 1) {
    sum += __shfl_xor(sum, m);
    sq  += __shfl_xor(sq, m);
  }
  const float mu = sum * (1.0f / 1024.0f);
  const float var = sq * (1.0f / 1024.0f) - mu * mu;
  const float rs = rsqrtf(var + 1e-5f);
#pragma unroll
  for (int c = 0; c < 4; c++) {
    const int col = c * 256 + lane * 4;
    float4 gg = *(const float4*)(g + col);
    float4 bb = *(const float4*)(bvec + col);
    float4 ov;
    ov.x = (y[c * 4 + 0] - mu) * rs * gg.x + bb.x;
    ov.y = (y[c * 4 + 1] - mu) * rs * gg.y + bb.y;
    ov.z = (y[c * 4 + 2] - mu) * rs * gg.z + bb.z;
    ov.w = (y[c * 4 + 3] - mu) * rs * gg.w + bb.w;
    *(float4*)(out + rb + col) = ov;
  }
}

extern "C" void kernel_launch(void* const* d_in, const int* in_sizes, int n_in,
                              void* d_out, int out_size, void* d_ws, size_t ws_size,
                              hipStream_t stream) {
  const float* slots = (const float*)d_in[0];
  const float* in_w  = (const float*)d_in[1];
  const float* in_b  = (const float*)d_in[2];
  const float* out_w = (const float*)d_in[3];
  const float* out_b = (const float*)d_in[4];
  const float* ln_g  = (const float*)d_in[5];
  const float* ln_b  = (const float*)d_in[6];
  float* out = (float*)d_out;

  const int M = 32768 * 3;  // 98304 rows

  // workspace layout:
  //   Abf   [M*1024 bf16] = 201,326,592 B   (stays live: bf16 slots for ln)
  //   Winb  [3072*1024]   =   6,291,456 B
  //   Woutb [1024*1024]   =   2,097,152 B
  //   qkv   [M*3072]      = 603,979,776 B   (k-slice reused as ctx,
  //                                          q-slice reused as attn_out)
  char* ws = (char*)d_ws;
  u16* Abf   = (u16*)ws;
  u16* Winb  = (u16*)(ws + 201326592);
  u16* Woutb = (u16*)(ws + 207618048);
  u16* qkv   = (u16*)(ws + 209715200);

  cvt_f32_bf16_kernel<<<2048, 256, 0, stream>>>(slots, Abf, M * 1024 / 4);
  cvt_f32_bf16_kernel<<<2048, 256, 0, stream>>>(in_w, Winb, 3072 * 1024 / 4);
  cvt_f32_bf16_kernel<<<1024, 256, 0, stream>>>(out_w, Woutb, 1024 * 1024 / 4);

  // qkv = Abf @ Winb^T + in_b : M x 3072, tiles (M/128=768) x (3072/256=12)
  gemm_bt_bias<<<768 * 12, 512, 0, stream>>>(
      Abf, Winb, in_b, qkv, 3072, 1024, 1024, 3072, 12);

  // ctx written in-place into the k-slice of qkv
  attn3_kernel<<<2048, 256, 0, stream>>>(qkv);

  // attn_out = ctx @ Woutb^T + out_b -> q-slice of qkv : tiles 768 x 4
  gemm_bt_bias<<<768 * 4, 512, 0, stream>>>(
      qkv + 1024, Woutb, out_b, qkv, 1024, 1024, 3072, 3072, 4);

  // out = LN(slots_bf16 + attn_out) * g + b
  ln_kernel<<<M / 4, 256, 0, stream>>>(Abf, qkv, ln_g, ln_b, out);
}

// Round 15
// 1310.505 us; speedup vs baseline: 1.3014x; 1.3014x over previous
//
#include <hip/hip_runtime.h>
#include <stdint.h>

typedef unsigned short u16;
typedef float f32x4 __attribute__((ext_vector_type(4)));
typedef short bf16x8 __attribute__((ext_vector_type(8)));

// ---------- helpers ----------
__device__ __forceinline__ u16 f2bu(float f) {           // fp32 -> bf16 (RNE)
  uint32_t x = __builtin_bit_cast(uint32_t, f);
  x += 0x7fffu + ((x >> 16) & 1u);
  return (u16)(x >> 16);
}
__device__ __forceinline__ float b2f(u16 u) {            // bf16 -> fp32 (exact)
  return __builtin_bit_cast(float, (uint32_t)u << 16);
}
__device__ __forceinline__ void gll16(const void* g, void* l) {
  __builtin_amdgcn_global_load_lds(
      (const __attribute__((address_space(1))) void*)g,
      (__attribute__((address_space(3))) void*)l, 16, 0, 0);
}

// ---------- fused fp32 -> bf16 convert (3 tensors, one launch) ----------
__global__ __launch_bounds__(256) void cvt_all_kernel(
    const float* __restrict__ s, u16* __restrict__ os, int ns4,
    const float* __restrict__ w1, u16* __restrict__ o1, int n14,
    const float* __restrict__ w2, u16* __restrict__ o2, int n24) {
  const int stride = gridDim.x * 256;
  const int t0 = blockIdx.x * 256 + threadIdx.x;
  for (int i = t0; i < ns4; i += stride) {
    float4 f = reinterpret_cast<const float4*>(s)[i];
    ushort4 o;
    o.x = f2bu(f.x); o.y = f2bu(f.y); o.z = f2bu(f.z); o.w = f2bu(f.w);
    reinterpret_cast<ushort4*>(os)[i] = o;
  }
  for (int i = t0; i < n14; i += stride) {
    float4 f = reinterpret_cast<const float4*>(w1)[i];
    ushort4 o;
    o.x = f2bu(f.x); o.y = f2bu(f.y); o.z = f2bu(f.z); o.w = f2bu(f.w);
    reinterpret_cast<ushort4*>(o1)[i] = o;
  }
  for (int i = t0; i < n24; i += stride) {
    float4 f = reinterpret_cast<const float4*>(w2)[i];
    ushort4 o;
    o.x = f2bu(f.x); o.y = f2bu(f.y); o.z = f2bu(f.z); o.w = f2bu(f.w);
    reinterpret_cast<ushort4*>(o2)[i] = o;
  }
}

// ---------- 256x256 GEMM, 16 waves, wave-tile 64x64, BK=64 (r12 best) ----
// C[m,n] = sum_k A[m,k]*B[n,k] + bias[n], bf16 in/out, fp32 accum.
// 624us / 991TF / MfmaUtil 46% / occupancy 44.5% / 0 conflicts (r12).
// BK=64 dbuf (128KB), ONE barrier per K-tile, two dependence-free kh rounds,
// both-sides 3-bit involution slot3' = slot3 ^ (row&7), coalesced staging,
// XCD swizzle. VGPR 60 + 64 AGPR = 124 -> 4 waves/SIMD (the 128-reg cap is
// why no further fragment hoisting fits at this geometry).
__global__ __launch_bounds__(1024, 4) void gemm256_bt_bias(
    const u16* __restrict__ A, const u16* __restrict__ Bw,
    const float* __restrict__ bias, u16* __restrict__ C,
    int N, int K, int lda, int ldc, int ntn) {
  __shared__ u16 lds[2][2][16384];   // [buf][A=0/B=1][256 rows * 64 cols]
  const int tid = threadIdx.x;
  const int lane = tid & 63, wid = tid >> 6;   // wid 0..15
  const int wr = wid >> 2, wc = wid & 3;        // wave grid 4 (M) x 4 (N)
  const int fr = lane & 15, kg = lane >> 4;

  // XCD-aware swizzle (grid % 8 == 0 for both calls)
  const int cpx = (int)gridDim.x >> 3;
  const int bid = blockIdx.x;
  const int sid = (bid & 7) * cpx + (bid >> 3);
  const int mt = sid / ntn, nt = sid % ntn;

  // staging: slot s in {tid, tid+1024}; row = s>>3, slot3 = s&7.
  const int srow = tid >> 3;                    // 0..127 (slot 2 adds 128)
  const int sc8 = (tid & 7) ^ (srow & 7);
  const u16* Ag = A + (size_t)(mt * 256 + srow) * lda + sc8 * 8;
  const u16* Bg = Bw + (size_t)(nt * 256 + srow) * K + sc8 * 8;
  const size_t arstep = (size_t)128 * lda;     // +128 rows for slot 2
  const size_t brstep = (size_t)128 * K;

  // fragment read bases (u16, row stride 64); slot3 = ((kh<<2)|kg) ^ (fr&7)
  const int fx = fr & 7;
  const int aoff = (wr * 64 + fr) * 64;         // + mi*1024 + slot3*8
  const int boff = (wc * 64 + fr) * 64;         // + nj*1024 + slot3*8

  f32x4 acc[4][4];
#pragma unroll
  for (int i = 0; i < 4; i++)
#pragma unroll
    for (int j = 0; j < 4; j++) acc[i][j] = f32x4{0.f, 0.f, 0.f, 0.f};

  const int NT = K >> 6;

#define STAGE(b, kt) do {                                                  \
    const u16* a_ = Ag + (size_t)(kt) * 64;                                \
    const u16* b_ = Bg + (size_t)(kt) * 64;                                \
    gll16(a_,          &lds[(b)][0][wid * 512]);                           \
    gll16(a_ + arstep, &lds[(b)][0][8192 + wid * 512]);                    \
    gll16(b_,          &lds[(b)][1][wid * 512]);                           \
    gll16(b_ + brstep, &lds[(b)][1][8192 + wid * 512]);                    \
  } while (0)

  STAGE(0, 0);
  __syncthreads();              // tile 0 landed (vmcnt(0) drain)

  for (int t = 0; t < NT; t++) {
    const int cur = t & 1;
    if (t + 1 < NT) STAGE(cur ^ 1, t + 1);   // prefetch next tile
    const u16* As = &lds[cur][0][0];
    const u16* Bs = &lds[cur][1][0];
#pragma unroll
    for (int kh = 0; kh < 2; kh++) {         // two k-sub rounds, no barrier
      const int slot3 = ((kh << 2) | kg) ^ fx;
      bf16x8 a[4], b[4];
#pragma unroll
      for (int nj = 0; nj < 4; nj++)
        b[nj] = *(const bf16x8*)&Bs[boff + nj * 1024 + slot3 * 8];
#pragma unroll
      for (int mi = 0; mi < 4; mi++)
        a[mi] = *(const bf16x8*)&As[aoff + mi * 1024 + slot3 * 8];
      __builtin_amdgcn_s_setprio(1);
#pragma unroll
      for (int mi = 0; mi < 4; mi++)
#pragma unroll
        for (int nj = 0; nj < 4; nj++)
          acc[mi][nj] = __builtin_amdgcn_mfma_f32_16x16x32_bf16(
              a[mi], b[nj], acc[mi][nj], 0, 0, 0);
      __builtin_amdgcn_s_setprio(0);
    }
    __syncthreads();   // next tile landed + this tile's reads done (WAR safe)
  }
#undef STAGE

  // C/D layout per 16x16 frag: col = lane&15, row = (lane>>4)*4 + reg
  const int crow0 = mt * 256 + wr * 64 + kg * 4;
  const int ccol0 = nt * 256 + wc * 64 + fr;
#pragma unroll
  for (int nj = 0; nj < 4; nj++) {
    const int col = ccol0 + nj * 16;
    const float bb = bias[col];
#pragma unroll
    for (int mi = 0; mi < 4; mi++) {
      const int r0 = crow0 + mi * 16;
      f32x4 v = acc[mi][nj];
#pragma unroll
      for (int r = 0; r < 4; r++)
        C[(size_t)(r0 + r) * ldc + col] = f2bu(v[r] + bb);
    }
  }
}

// ---------- tiny attention: S=3, 16 heads of d=64, 16B/lane ----------
// Wave handles (batch, half): 8 heads x 512 cols; lane = head_sub(3b) |
// col8(3b): cols head_sub*64 + col8*8, 16B loads. 8-lane shfl dot reduce.
// Writes ctx IN-PLACE into the k-slice (cols 1024..2047) of qkv.
__global__ __launch_bounds__(256) void attn3_kernel(
    u16* __restrict__ qkv) {
  const int tid = threadIdx.x;
  const int lane = tid & 63, wid = tid >> 6;
  const int nunit = 32768 * 2;
  for (int unit = blockIdx.x * 4 + wid; unit < nunit; unit += gridDim.x * 4) {
    const int b = unit >> 1, hf = unit & 1;
    const int colb = hf * 512 + (lane >> 3) * 64 + (lane & 7) * 8;
    const size_t base = (size_t)b * 9216 + colb;

    float q[3][8], k[3][8], v[3][8];
#pragma unroll
    for (int s = 0; s < 3; s++) {
      bf16x8 uq = *(const bf16x8*)(qkv + base + (size_t)s * 3072);
      bf16x8 uk = *(const bf16x8*)(qkv + base + (size_t)s * 3072 + 1024);
      bf16x8 uv = *(const bf16x8*)(qkv + base + (size_t)s * 3072 + 2048);
#pragma unroll
      for (int e = 0; e < 8; e++) {
        q[s][e] = b2f((u16)uq[e]);
        k[s][e] = b2f((u16)uk[e]);
        v[s][e] = b2f((u16)uv[e]);
      }
    }

    float sc[3][3];
#pragma unroll
    for (int i = 0; i < 3; i++)
#pragma unroll
      for (int j = 0; j < 3; j++) {
        float p = 0.f;
#pragma unroll
        for (int e = 0; e < 8; e++) p += q[i][e] * k[j][e];
        p += __shfl_xor(p, 1);
        p += __shfl_xor(p, 2);
        p += __shfl_xor(p, 4);   // 8-lane group = one head's 64 dims
        sc[i][j] = p;
      }

    float o[3][8];
#pragma unroll
    for (int i = 0; i < 3; i++) {
      float mx = fmaxf(sc[i][0], fmaxf(sc[i][1], sc[i][2]));
      float e0 = __expf((sc[i][0] - mx) * 0.125f);
      float e1 = __expf((sc[i][1] - mx) * 0.125f);
      float e2 = __expf((sc[i][2] - mx) * 0.125f);
      float inv = 1.f / (e0 + e1 + e2);
      e0 *= inv; e1 *= inv; e2 *= inv;
#pragma unroll
      for (int e = 0; e < 8; e++)
        o[i][e] = e0 * v[0][e] + e1 * v[1][e] + e2 * v[2][e];
    }

#pragma unroll
    for (int i = 0; i < 3; i++) {
      bf16x8 ov;
#pragma unroll
      for (int e = 0; e < 8; e++) ov[e] = (short)f2bu(o[i][e]);
      *(bf16x8*)(qkv + base + (size_t)i * 3072 + 1024) = ov;
    }
  }
}

// ---------- residual + LayerNorm: wave per row of 1024, 16B loads ----------
__global__ __launch_bounds__(256) void ln_kernel(
    const u16* __restrict__ slots_bf, const u16* __restrict__ ao,
    const float* __restrict__ g, const float* __restrict__ bvec,
    float* __restrict__ out) {
  const int tid = threadIdx.x;
  const int lane = tid & 63, wid = tid >> 6;
  const int row = blockIdx.x * 4 + wid;
  const size_t rb = (size_t)row * 1024;
  const size_t ab = (size_t)row * 3072;

  float y[16];
  float sum = 0.f, sq = 0.f;
#pragma unroll
  for (int c = 0; c < 2; c++) {
    const int col = c * 512 + lane * 8;
    bf16x8 s8 = *(const bf16x8*)(slots_bf + rb + col);
    bf16x8 a8 = *(const bf16x8*)(ao + ab + col);
#pragma unroll
    for (int e = 0; e < 8; e++) {
      float yv = b2f((u16)s8[e]) + b2f((u16)a8[e]);
      y[c * 8 + e] = yv;
      sum += yv;
      sq += yv * yv;
    }
  }
#pragma unroll
  for (int m = 1; m < 64; m <<= 1) {
    sum += __shfl_xor(sum, m);
    sq  += __shfl_xor(sq, m);
  }
  const float mu = sum * (1.0f / 1024.0f);
  const float var = sq * (1.0f / 1024.0f) - mu * mu;
  const float rs = rsqrtf(var + 1e-5f);
#pragma unroll
  for (int c = 0; c < 2; c++) {
    const int col = c * 512 + lane * 8;
#pragma unroll
    for (int h = 0; h < 2; h++) {
      float4 gg = *(const float4*)(g + col + h * 4);
      float4 bb = *(const float4*)(bvec + col + h * 4);
      float4 ov;
      ov.x = (y[c * 8 + h * 4 + 0] - mu) * rs * gg.x + bb.x;
      ov.y = (y[c * 8 + h * 4 + 1] - mu) * rs * gg.y + bb.y;
      ov.z = (y[c * 8 + h * 4 + 2] - mu) * rs * gg.z + bb.z;
      ov.w = (y[c * 8 + h * 4 + 3] - mu) * rs * gg.w + bb.w;
      *(float4*)(out + rb + col + h * 4) = ov;
    }
  }
}

extern "C" void kernel_launch(void* const* d_in, const int* in_sizes, int n_in,
                              void* d_out, int out_size, void* d_ws, size_t ws_size,
                              hipStream_t stream) {
  const float* slots = (const float*)d_in[0];
  const float* in_w  = (const float*)d_in[1];
  const float* in_b  = (const float*)d_in[2];
  const float* out_w = (const float*)d_in[3];
  const float* out_b = (const float*)d_in[4];
  const float* ln_g  = (const float*)d_in[5];
  const float* ln_b  = (const float*)d_in[6];
  float* out = (float*)d_out;

  const int M = 32768 * 3;  // 98304 rows

  // workspace layout:
  //   Abf   [M*1024 bf16] = 201,326,592 B   (stays live: bf16 slots for ln)
  //   Winb  [3072*1024]   =   6,291,456 B
  //   Woutb [1024*1024]   =   2,097,152 B
  //   qkv   [M*3072]      = 603,979,776 B   (k-slice reused as ctx,
  //                                          q-slice reused as attn_out)
  char* ws = (char*)d_ws;
  u16* Abf   = (u16*)ws;
  u16* Winb  = (u16*)(ws + 201326592);
  u16* Woutb = (u16*)(ws + 207618048);
  u16* qkv   = (u16*)(ws + 209715200);

  cvt_all_kernel<<<2048, 256, 0, stream>>>(
      slots, Abf, M * 1024 / 4,
      in_w, Winb, 3072 * 1024 / 4,
      out_w, Woutb, 1024 * 1024 / 4);

  // qkv = Abf @ Winb^T + in_b : M x 3072, tiles 384 x 12
  gemm256_bt_bias<<<384 * 12, 1024, 0, stream>>>(
      Abf, Winb, in_b, qkv, 3072, 1024, 1024, 3072, 12);

  // ctx written in-place into the k-slice of qkv
  attn3_kernel<<<2048, 256, 0, stream>>>(qkv);

  // attn_out = ctx @ Woutb^T + out_b -> q-slice of qkv : M x 1024, tiles 384 x 4
  gemm256_bt_bias<<<384 * 4, 1024, 0, stream>>>(
      qkv + 1024, Woutb, out_b, qkv, 1024, 1024, 3072, 3072, 4);

  // out = LN(slots_bf16 + attn_out) * g + b
  ln_kernel<<<M / 4, 256, 0, stream>>>(Abf, qkv, ln_g, ln_b, out);
}